// Round 8
// baseline (289.674 us; speedup 1.0000x reference)
//
#include <hip/hip_runtime.h>
#include <hip/hip_bf16.h>
#include <cstdint>

#define HDIM 128
#define NEG_SLOPE 0.01f

__device__ __forceinline__ unsigned short f2bf(float f) {
    __hip_bfloat16 b = __float2bfloat16(f);
    return *reinterpret_cast<unsigned short*>(&b);
}

// ---------------------------------------------------------------------------
// K0: row_ptr build. start_nodes is sorted; row_ptr[n] = lower_bound(start, n).
// ---------------------------------------------------------------------------
__global__ __launch_bounds__(256)
void k0_rowptr(const int* __restrict__ start, int* __restrict__ row_ptr,
               int N, int E) {
    int e = blockIdx.x * 256 + threadIdx.x;
    if (e >= E) return;
    int s = start[e];
    if (e == 0) {
        for (int n = 0; n <= s; ++n) row_ptr[n] = 0;
    }
    int snext = (e + 1 < E) ? start[e + 1] : N;
    for (int n = s + 1; n <= snext; ++n) row_ptr[n] = e + 1;
}

// ---------------------------------------------------------------------------
// K12: PARALLEL fusion of two independent phases in one launch:
//   GEMM blocks : messages = node_emb @ W1^T (bf16 store) + a_src/a_dst dots
//   STREAM blocks: praw[e] = edge_emb[e] . W2[256:384]   (raw dot; leaky+bias
//                  deferred to K3 so this branch needs nothing from the GEMM)
// Interleaved 1 GEMM : 3 STREAM so both are co-resident from t=0 (GEMM is
// VALU/LDS-bound, stream is HBM-bound -> they overlap on a CU).
// Stream branch: ONE EDGE PER THREAD (8 x float4 independent loads = 512B in
// flight per thread) -> saturates HBM even at LDS-limited 2 blocks/CU.
// ---------------------------------------------------------------------------
#define K1_ROWS 64

__global__ __launch_bounds__(256, 2)
void k12_parallel(const float* __restrict__ A, const float* __restrict__ W1,
                  const float* __restrict__ W2, unsigned short* __restrict__ msgb,
                  float* __restrict__ a_src, float* __restrict__ a_dst, int N,
                  const float* __restrict__ edge_emb, float* __restrict__ praw,
                  int E, int Gg, int interleave) {
    __shared__ float smem[HDIM * HDIM + 2 * 64 * 17];   // 72.5 KB (GEMM max)

    const int bid = blockIdx.x;
    const int tid = threadIdx.x;

    int gemm_id = -1, stream_id = 0;
    if (interleave) {
        if (bid < 4 * Gg) {
            if ((bid & 3) == 0) gemm_id = bid >> 2;
            else stream_id = (bid >> 2) * 3 + (bid & 3) - 1;
        } else {
            stream_id = 3 * Gg + (bid - 4 * Gg);
        }
    } else {
        if (bid < Gg) gemm_id = bid;
        else stream_id = bid - Gg;
    }

    if (gemm_id < 0) {
        // ---------------- STREAM branch: 256 edges per block ----------------
        float* w2s = smem;   // 128 floats of W2[2H:]
        if (tid < 32)
            *reinterpret_cast<float4*>(&w2s[tid * 4]) =
                reinterpret_cast<const float4*>(W2 + 2 * HDIM)[tid];
        __syncthreads();

        int e = stream_id * 256 + tid;
        if (e < E) {
            const float4* row = reinterpret_cast<const float4*>(edge_emb) + (size_t)e * 32;
            float p = 0.f;
#pragma unroll 8
            for (int g = 0; g < 32; ++g) {
                float4 ev = row[g];
                float4 w  = *reinterpret_cast<const float4*>(&w2s[g * 4]);
                p += ev.x * w.x + ev.y * w.y + ev.z * w.z + ev.w * w.w;
            }
            praw[e] = p;
        }
        return;
    }

    // ------------------------- GEMM branch -------------------------
    float* W1s   = smem;                 // [128][128], XOR-swizzled granules
    float* red_a = smem + HDIM * HDIM;   // [64][17]
    float* red_b = red_a + 64 * 17;

    const int row0 = gemm_id * K1_ROWS;

    for (int i = tid; i < HDIM * HDIM / 4; i += 256) {
        int h = i >> 5;
        int g = i & 31;
        float4 v = reinterpret_cast<const float4*>(W1)[i];
        int gs = g ^ ((h >> 3) & 3);
        *reinterpret_cast<float4*>(&W1s[h * HDIM + gs * 4]) = v;
    }
    __syncthreads();

    const int row_t = tid & 15;
    const int col_t = tid >> 4;
    const int h0 = col_t * 8;
    const int sxor = col_t & 3;
    const int wbase = h0 * HDIM;

    int gr[4];
#pragma unroll
    for (int r = 0; r < 4; ++r) {
        int g = row0 + row_t + 16 * r;
        gr[r] = (g < N) ? g : (N - 1);
    }

    float acc[4][8];
#pragma unroll
    for (int r = 0; r < 4; ++r)
#pragma unroll
        for (int c = 0; c < 8; ++c) acc[r][c] = 0.f;

#pragma unroll 2
    for (int k0 = 0; k0 < HDIM; k0 += 4) {
        const int kk = (((k0 >> 2) ^ sxor) << 2);
        float4 a[4];
#pragma unroll
        for (int r = 0; r < 4; ++r)
            a[r] = *reinterpret_cast<const float4*>(&A[(size_t)gr[r] * HDIM + k0]);
#pragma unroll
        for (int c = 0; c < 8; ++c) {
            float4 w = *reinterpret_cast<const float4*>(&W1s[wbase + c * HDIM + kk]);
#pragma unroll
            for (int r = 0; r < 4; ++r) {
                acc[r][c] += a[r].x * w.x + a[r].y * w.y + a[r].z * w.z + a[r].w * w.w;
            }
        }
    }

    float pa[4], pb[4];
#pragma unroll
    for (int r = 0; r < 4; ++r) { pa[r] = 0.f; pb[r] = 0.f; }
#pragma unroll
    for (int c = 0; c < 8; ++c) {
        float wa = W2[h0 + c];
        float wb = W2[HDIM + h0 + c];
#pragma unroll
        for (int r = 0; r < 4; ++r) {
            pa[r] += acc[r][c] * wa;
            pb[r] += acc[r][c] * wb;
        }
    }

#pragma unroll
    for (int r = 0; r < 4; ++r) {
        int g = row0 + row_t + 16 * r;
        if (g < N) {
            uint4 pk;
            pk.x = (uint32_t)f2bf(acc[r][0]) | ((uint32_t)f2bf(acc[r][1]) << 16);
            pk.y = (uint32_t)f2bf(acc[r][2]) | ((uint32_t)f2bf(acc[r][3]) << 16);
            pk.z = (uint32_t)f2bf(acc[r][4]) | ((uint32_t)f2bf(acc[r][5]) << 16);
            pk.w = (uint32_t)f2bf(acc[r][6]) | ((uint32_t)f2bf(acc[r][7]) << 16);
            *reinterpret_cast<uint4*>(&msgb[(size_t)g * HDIM + h0]) = pk;
        }
        red_a[(row_t + 16 * r) * 17 + col_t] = pa[r];
        red_b[(row_t + 16 * r) * 17 + col_t] = pb[r];
    }
    __syncthreads();

    if (tid < K1_ROWS) {
        int g = row0 + tid;
        if (g < N) {
            float sa = 0.f, sb = 0.f;
#pragma unroll
            for (int j = 0; j < 16; ++j) {
                sa += red_a[tid * 17 + j];
                sb += red_b[tid * 17 + j];
            }
            a_src[g] = sa;
            a_dst[g] = sb;
        }
    }
}

// ---------------------------------------------------------------------------
// K3: segment softmax + weighted aggregate. One WAVE per node; each lane owns
// 2 output dims (uint = 2 bf16 per gather row -> 256B coalesced). Softmax
// state (m,s,lv) is wave-uniform -> replicated per lane, ZERO shuffles.
// l = leaky(praw[e] + a_src[n] + a_dst[end[e]]). Batched 8 edges; validity
// branches are wave-uniform (no divergence). Online rescale once per batch.
// ---------------------------------------------------------------------------
#define KB 8

__global__ __launch_bounds__(256)
void k3_aggregate(const float* __restrict__ praw, const int* __restrict__ row_ptr,
                  const int* __restrict__ end, const float* __restrict__ a_src,
                  const float* __restrict__ a_dst,
                  const unsigned short* __restrict__ msgb,
                  float* __restrict__ out, int N) {
    const int wid  = threadIdx.x >> 6;
    const int lane = threadIdx.x & 63;
    const int n = blockIdx.x * 4 + wid;
    if (n >= N) return;

    const int lo = row_ptr[n];
    const int hi = row_ptr[n + 1];

    if (lo >= hi) {
        *reinterpret_cast<float2*>(&out[(size_t)n * HDIM + lane * 2]) =
            make_float2(0.f, 0.f);
        return;
    }

    const float asrc = a_src[n];
    float m = -3.0e38f;
    float s = 0.f;
    float2 acc = make_float2(0.f, 0.f);

    for (int base = lo; base < hi; base += KB) {
        float lv[KB];
        uint32_t mu[KB];
        const int cnt = hi - base;   // wave-uniform

        // pass A: independent loads (8 gather rows in flight)
#pragma unroll
        for (int i = 0; i < KB; ++i) {
            if (i < cnt) {           // wave-uniform branch
                int e = base + i;
                int d = end[e];
                mu[i] = reinterpret_cast<const uint32_t*>(msgb)[(size_t)d * 64 + lane];
                float l = praw[e] + asrc + a_dst[d];
                lv[i] = (l >= 0.f) ? l : NEG_SLOPE * l;
            } else {
                mu[i] = 0;
                lv[i] = -3.0e38f;
            }
        }

        // pass B: batch max, one rescale, independent accumulates
        float bm = lv[0];
#pragma unroll
        for (int i = 1; i < KB; ++i) bm = fmaxf(bm, lv[i]);
        float mn = fmaxf(m, bm);
        float sc = __expf(m - mn);   // 0 on first batch

        float bs = 0.f;
        float2 ba = make_float2(0.f, 0.f);
#pragma unroll
        for (int i = 0; i < KB; ++i) {
            float w = __expf(lv[i] - mn);            // masked: -> 0
            bs += w;
            ba.x += w * __uint_as_float(mu[i] << 16);
            ba.y += w * __uint_as_float(mu[i] & 0xffff0000u);
        }
        s = s * sc + bs;
        acc.x = acc.x * sc + ba.x;
        acc.y = acc.y * sc + ba.y;
        m = mn;
    }

    const float inv = 1.f / s;
    *reinterpret_cast<float2*>(&out[(size_t)n * HDIM + lane * 2]) =
        make_float2(acc.x * inv, acc.y * inv);
}

// ---------------------------------------------------------------------------
extern "C" void kernel_launch(void* const* d_in, const int* in_sizes, int n_in,
                              void* d_out, int out_size, void* d_ws, size_t ws_size,
                              hipStream_t stream) {
    const float* node_emb = (const float*)d_in[0];
    const float* edge_emb = (const float*)d_in[1];
    const int*   start    = (const int*)d_in[2];
    const int*   end      = (const int*)d_in[3];
    const float* W1       = (const float*)d_in[4];
    const float* W2       = (const float*)d_in[5];
    float* out = (float*)d_out;

    const int N = in_sizes[0] / HDIM;
    const int E = in_sizes[2];

    uint8_t* ws = (uint8_t*)d_ws;
    size_t off = 0;
    auto alloc = [&](size_t bytes) {
        void* p = ws + off;
        off = (off + bytes + 511) & ~(size_t)511;
        return p;
    };
    unsigned short* msgb = (unsigned short*)alloc((size_t)N * HDIM * sizeof(unsigned short));
    float* a_src   = (float*)alloc((size_t)N * sizeof(float));
    float* a_dst   = (float*)alloc((size_t)N * sizeof(float));
    float* praw    = (float*)alloc((size_t)E * sizeof(float));
    int*   row_ptr = (int*)alloc((size_t)(N + 1) * sizeof(int));

    const int Gg = (N + K1_ROWS - 1) / K1_ROWS;          // GEMM blocks
    const int Gs = (E + 255) / 256;                      // stream blocks
    const int interleave = (Gs >= 3 * Gg) ? 1 : 0;       // 1:3 mapping valid?

    // K0: row_ptr
    k0_rowptr<<<(E + 255) / 256, 256, 0, stream>>>(start, row_ptr, N, E);
    // K12: GEMM || edge-dot stream (independent phases, one launch)
    k12_parallel<<<Gg + Gs, 256, 0, stream>>>(node_emb, W1, W2, msgb, a_src,
                                              a_dst, N, edge_emb, praw, E, Gg,
                                              interleave);
    // K3: gather + softmax + aggregate
    k3_aggregate<<<(N + 3) / 4, 256, 0, stream>>>(praw, row_ptr, end, a_src,
                                                  a_dst, msgb, out, N);
}

// Round 9
// 208.550 us; speedup vs baseline: 1.3890x; 1.3890x over previous
//
#include <hip/hip_runtime.h>
#include <hip/hip_bf16.h>
#include <cstdint>

#define HDIM 128
#define NEG_SLOPE 0.01f

__device__ __forceinline__ unsigned short f2bf(float f) {
    __hip_bfloat16 b = __float2bfloat16(f);
    return *reinterpret_cast<unsigned short*>(&b);
}

// ---------------------------------------------------------------------------
// K2: edge-dot stream + row_ptr build, one pass over edges.
//   praw[e] = edge_emb[e] . W2[256:384]   (leaky+bias deferred to K3)
// Half-wave (32 lanes x float4) per edge -> each wave reads 2 consecutive
// 512B rows = 1KB contiguous. No LDS, low VGPR -> max occupancy, HBM-bound.
// row_ptr: one thread per edge in the first ceil(E/256) blocks (start sorted).
// ---------------------------------------------------------------------------
__global__ __launch_bounds__(256)
void k2_stream_rowptr(const float* __restrict__ edge_emb,
                      const float* __restrict__ W2,
                      const int* __restrict__ start, int* __restrict__ row_ptr,
                      float* __restrict__ praw, int N, int E) {
    const int tid = threadIdx.x;
    const int bid = blockIdx.x;

    // ---- row_ptr part (first E/256 blocks only) ----
    int gt = bid * 256 + tid;
    if (gt < E) {
        int s = start[gt];
        if (gt == 0) {
            for (int n = 0; n <= s; ++n) row_ptr[n] = 0;
        }
        int snext = (gt + 1 < E) ? start[gt + 1] : N;
        for (int n = s + 1; n <= snext; ++n) row_ptr[n] = gt + 1;
    }

    // ---- stream part: 8 edges per block ----
    const int sub = tid & 31;
    const int e = bid * 8 + (tid >> 5);
    if (e < E) {
        float4 ev = reinterpret_cast<const float4*>(edge_emb)[(size_t)e * 32 + sub];
        float4 wc = reinterpret_cast<const float4*>(W2 + 2 * HDIM)[sub];
        float p = ev.x * wc.x + ev.y * wc.y + ev.z * wc.z + ev.w * wc.w;
#pragma unroll
        for (int k = 1; k <= 16; k <<= 1) p += __shfl_xor(p, k);  // within half
        if (sub == 0) praw[e] = p;
    }
}

// ---------------------------------------------------------------------------
// K1: messages = node_emb @ W1^T, stored as BF16 (gather table for K3),
// fused per-node dots a_src[n] = msg·W2[0:128], a_dst[n] = msg·W2[128:256].
// W1 in LDS with bijective XOR column-granule swizzle (conflict-free reads).
// ---------------------------------------------------------------------------
#define K1_ROWS 64

__global__ __launch_bounds__(256, 2)
void k1_messages(const float* __restrict__ A, const float* __restrict__ W1,
                 const float* __restrict__ W2, unsigned short* __restrict__ msgb,
                 float* __restrict__ a_src, float* __restrict__ a_dst, int N) {
    __shared__ float W1s[HDIM * HDIM];   // XOR-swizzled granules
    __shared__ float red_a[64 * 17];
    __shared__ float red_b[64 * 17];

    const int tid  = threadIdx.x;
    const int row0 = blockIdx.x * K1_ROWS;

    for (int i = tid; i < HDIM * HDIM / 4; i += 256) {
        int h = i >> 5;
        int g = i & 31;
        float4 v = reinterpret_cast<const float4*>(W1)[i];
        int gs = g ^ ((h >> 3) & 3);
        *reinterpret_cast<float4*>(&W1s[h * HDIM + gs * 4]) = v;
    }
    __syncthreads();

    const int row_t = tid & 15;
    const int col_t = tid >> 4;
    const int h0 = col_t * 8;
    const int sxor = col_t & 3;
    const int wbase = h0 * HDIM;

    int gr[4];
#pragma unroll
    for (int r = 0; r < 4; ++r) {
        int g = row0 + row_t + 16 * r;
        gr[r] = (g < N) ? g : (N - 1);
    }

    float acc[4][8];
#pragma unroll
    for (int r = 0; r < 4; ++r)
#pragma unroll
        for (int c = 0; c < 8; ++c) acc[r][c] = 0.f;

#pragma unroll 2
    for (int k0 = 0; k0 < HDIM; k0 += 4) {
        const int kk = (((k0 >> 2) ^ sxor) << 2);
        float4 a[4];
#pragma unroll
        for (int r = 0; r < 4; ++r)
            a[r] = *reinterpret_cast<const float4*>(&A[(size_t)gr[r] * HDIM + k0]);
#pragma unroll
        for (int c = 0; c < 8; ++c) {
            float4 w = *reinterpret_cast<const float4*>(&W1s[wbase + c * HDIM + kk]);
#pragma unroll
            for (int r = 0; r < 4; ++r) {
                acc[r][c] += a[r].x * w.x + a[r].y * w.y + a[r].z * w.z + a[r].w * w.w;
            }
        }
    }

    float pa[4], pb[4];
#pragma unroll
    for (int r = 0; r < 4; ++r) { pa[r] = 0.f; pb[r] = 0.f; }
#pragma unroll
    for (int c = 0; c < 8; ++c) {
        float wa = W2[h0 + c];
        float wb = W2[HDIM + h0 + c];
#pragma unroll
        for (int r = 0; r < 4; ++r) {
            pa[r] += acc[r][c] * wa;
            pb[r] += acc[r][c] * wb;
        }
    }

    // direct bf16 store of msg rows
#pragma unroll
    for (int r = 0; r < 4; ++r) {
        int g = row0 + row_t + 16 * r;
        if (g < N) {
            uint4 pk;
            pk.x = (uint32_t)f2bf(acc[r][0]) | ((uint32_t)f2bf(acc[r][1]) << 16);
            pk.y = (uint32_t)f2bf(acc[r][2]) | ((uint32_t)f2bf(acc[r][3]) << 16);
            pk.z = (uint32_t)f2bf(acc[r][4]) | ((uint32_t)f2bf(acc[r][5]) << 16);
            pk.w = (uint32_t)f2bf(acc[r][6]) | ((uint32_t)f2bf(acc[r][7]) << 16);
            *reinterpret_cast<uint4*>(&msgb[(size_t)g * HDIM + h0]) = pk;
        }
        red_a[(row_t + 16 * r) * 17 + col_t] = pa[r];
        red_b[(row_t + 16 * r) * 17 + col_t] = pb[r];
    }
    __syncthreads();

    if (tid < K1_ROWS) {
        int g = row0 + tid;
        if (g < N) {
            float sa = 0.f, sb = 0.f;
#pragma unroll
            for (int j = 0; j < 16; ++j) {
                sa += red_a[tid * 17 + j];
                sb += red_b[tid * 17 + j];
            }
            a_src[g] = sa;
            a_dst[g] = sb;
        }
    }
}

// ---------------------------------------------------------------------------
// K3: segment softmax + weighted aggregate. One WAVE per node; each lane owns
// 2 output dims (uint = 2 bf16 per gather row -> 256B coalesced). Softmax
// state is wave-uniform -> replicated per lane, ZERO shuffles. Batched 8
// edges; validity branches wave-uniform. Online rescale once per batch.
// msgb table (12.8MB) is L3-resident here (no competing stream).
// ---------------------------------------------------------------------------
#define KB 8

__global__ __launch_bounds__(256)
void k3_aggregate(const float* __restrict__ praw, const int* __restrict__ row_ptr,
                  const int* __restrict__ end, const float* __restrict__ a_src,
                  const float* __restrict__ a_dst,
                  const unsigned short* __restrict__ msgb,
                  float* __restrict__ out, int N) {
    const int wid  = threadIdx.x >> 6;
    const int lane = threadIdx.x & 63;
    const int n = blockIdx.x * 4 + wid;
    if (n >= N) return;

    const int lo = row_ptr[n];
    const int hi = row_ptr[n + 1];

    if (lo >= hi) {
        *reinterpret_cast<float2*>(&out[(size_t)n * HDIM + lane * 2]) =
            make_float2(0.f, 0.f);
        return;
    }

    const float asrc = a_src[n];
    float m = -3.0e38f;
    float s = 0.f;
    float2 acc = make_float2(0.f, 0.f);

    for (int base = lo; base < hi; base += KB) {
        float lv[KB];
        uint32_t mu[KB];
        const int cnt = hi - base;   // wave-uniform

        // pass A: independent loads (8 gather rows in flight)
#pragma unroll
        for (int i = 0; i < KB; ++i) {
            if (i < cnt) {           // wave-uniform branch
                int e = base + i;
                int d = end[e];
                mu[i] = reinterpret_cast<const uint32_t*>(msgb)[(size_t)d * 64 + lane];
                float l = praw[e] + asrc + a_dst[d];
                lv[i] = (l >= 0.f) ? l : NEG_SLOPE * l;
            } else {
                mu[i] = 0;
                lv[i] = -3.0e38f;
            }
        }

        // pass B: batch max, one rescale, independent accumulates
        float bm = lv[0];
#pragma unroll
        for (int i = 1; i < KB; ++i) bm = fmaxf(bm, lv[i]);
        float mn = fmaxf(m, bm);
        float sc = __expf(m - mn);   // 0 on first batch

        float bs = 0.f;
        float2 ba = make_float2(0.f, 0.f);
#pragma unroll
        for (int i = 0; i < KB; ++i) {
            float w = __expf(lv[i] - mn);            // masked: -> 0
            bs += w;
            ba.x += w * __uint_as_float(mu[i] << 16);
            ba.y += w * __uint_as_float(mu[i] & 0xffff0000u);
        }
        s = s * sc + bs;
        acc.x = acc.x * sc + ba.x;
        acc.y = acc.y * sc + ba.y;
        m = mn;
    }

    const float inv = 1.f / s;
    *reinterpret_cast<float2*>(&out[(size_t)n * HDIM + lane * 2]) =
        make_float2(acc.x * inv, acc.y * inv);
}

// ---------------------------------------------------------------------------
extern "C" void kernel_launch(void* const* d_in, const int* in_sizes, int n_in,
                              void* d_out, int out_size, void* d_ws, size_t ws_size,
                              hipStream_t stream) {
    const float* node_emb = (const float*)d_in[0];
    const float* edge_emb = (const float*)d_in[1];
    const int*   start    = (const int*)d_in[2];
    const int*   end      = (const int*)d_in[3];
    const float* W1       = (const float*)d_in[4];
    const float* W2       = (const float*)d_in[5];
    float* out = (float*)d_out;

    const int N = in_sizes[0] / HDIM;
    const int E = in_sizes[2];

    uint8_t* ws = (uint8_t*)d_ws;
    size_t off = 0;
    auto alloc = [&](size_t bytes) {
        void* p = ws + off;
        off = (off + bytes + 511) & ~(size_t)511;
        return p;
    };
    unsigned short* msgb = (unsigned short*)alloc((size_t)N * HDIM * sizeof(unsigned short));
    float* a_src   = (float*)alloc((size_t)N * sizeof(float));
    float* a_dst   = (float*)alloc((size_t)N * sizeof(float));
    float* praw    = (float*)alloc((size_t)E * sizeof(float));
    int*   row_ptr = (int*)alloc((size_t)(N + 1) * sizeof(int));

    // K2: edge-dot stream + row_ptr (HBM-bound, runs first so K1's msgb
    // write stays L3-hot entering K3)
    k2_stream_rowptr<<<(E + 7) / 8, 256, 0, stream>>>(edge_emb, W2, start,
                                                      row_ptr, praw, N, E);
    // K1: messages (bf16) + fused fp32 a_src/a_dst
    k1_messages<<<(N + K1_ROWS - 1) / K1_ROWS, 256, 0, stream>>>(
        node_emb, W1, W2, msgb, a_src, a_dst, N);
    // K3: gather + softmax + aggregate (one wave per node)
    k3_aggregate<<<(N + 3) / 4, 256, 0, stream>>>(praw, row_ptr, end, a_src,
                                                  a_dst, msgb, out, N);
}

// Round 10
// 157.107 us; speedup vs baseline: 1.8438x; 1.3274x over previous
//
#include <hip/hip_runtime.h>
#include <hip/hip_bf16.h>
#include <cstdint>

#define HDIM 128
#define NEG_SLOPE 0.01f

__device__ __forceinline__ unsigned short f2bf(float f) {
    __hip_bfloat16 b = __float2bfloat16(f);
    return *reinterpret_cast<unsigned short*>(&b);
}

// DPP rotate-add within the 16-lane row: VALU pipe, replaces a DS shuffle.
template <int N>
__device__ __forceinline__ float dpp_ror_add(float v) {
    int r = __builtin_amdgcn_update_dpp(0, __float_as_int(v), 0x120 + N,
                                        0xF, 0xF, false);
    return v + __int_as_float(r);
}

// ---------------------------------------------------------------------------
// K0: row_ptr build. start_nodes is sorted; row_ptr[n] = lower_bound(start, n).
// ---------------------------------------------------------------------------
__global__ __launch_bounds__(256)
void k0_rowptr(const int* __restrict__ start, int* __restrict__ row_ptr,
               int N, int E) {
    int e = blockIdx.x * 256 + threadIdx.x;
    if (e >= E) return;
    int s = start[e];
    if (e == 0) {
        for (int n = 0; n <= s; ++n) row_ptr[n] = 0;
    }
    int snext = (e + 1 < E) ? start[e + 1] : N;
    for (int n = s + 1; n <= snext; ++n) row_ptr[n] = e + 1;
}

// ---------------------------------------------------------------------------
// K1: messages = node_emb @ W1^T, stored as BF16 (gather table for K23),
// fused per-node dots a_src[n] = msg·W2[0:128], a_dst[n] = msg·W2[128:256].
// W1 in LDS with bijective XOR column-granule swizzle (conflict-free reads).
// ---------------------------------------------------------------------------
#define K1_ROWS 64

__global__ __launch_bounds__(256, 2)
void k1_messages(const float* __restrict__ A, const float* __restrict__ W1,
                 const float* __restrict__ W2, unsigned short* __restrict__ msgb,
                 float* __restrict__ a_src, float* __restrict__ a_dst, int N) {
    __shared__ float W1s[HDIM * HDIM];   // XOR-swizzled granules
    __shared__ float red_a[64 * 17];
    __shared__ float red_b[64 * 17];

    const int tid  = threadIdx.x;
    const int row0 = blockIdx.x * K1_ROWS;

    for (int i = tid; i < HDIM * HDIM / 4; i += 256) {
        int h = i >> 5;
        int g = i & 31;
        float4 v = reinterpret_cast<const float4*>(W1)[i];
        int gs = g ^ ((h >> 3) & 3);
        *reinterpret_cast<float4*>(&W1s[h * HDIM + gs * 4]) = v;
    }
    __syncthreads();

    const int row_t = tid & 15;
    const int col_t = tid >> 4;
    const int h0 = col_t * 8;
    const int sxor = col_t & 3;
    const int wbase = h0 * HDIM;

    int gr[4];
#pragma unroll
    for (int r = 0; r < 4; ++r) {
        int g = row0 + row_t + 16 * r;
        gr[r] = (g < N) ? g : (N - 1);
    }

    float acc[4][8];
#pragma unroll
    for (int r = 0; r < 4; ++r)
#pragma unroll
        for (int c = 0; c < 8; ++c) acc[r][c] = 0.f;

#pragma unroll 2
    for (int k0 = 0; k0 < HDIM; k0 += 4) {
        const int kk = (((k0 >> 2) ^ sxor) << 2);
        float4 a[4];
#pragma unroll
        for (int r = 0; r < 4; ++r)
            a[r] = *reinterpret_cast<const float4*>(&A[(size_t)gr[r] * HDIM + k0]);
#pragma unroll
        for (int c = 0; c < 8; ++c) {
            float4 w = *reinterpret_cast<const float4*>(&W1s[wbase + c * HDIM + kk]);
#pragma unroll
            for (int r = 0; r < 4; ++r) {
                acc[r][c] += a[r].x * w.x + a[r].y * w.y + a[r].z * w.z + a[r].w * w.w;
            }
        }
    }

    float pa[4], pb[4];
#pragma unroll
    for (int r = 0; r < 4; ++r) { pa[r] = 0.f; pb[r] = 0.f; }
#pragma unroll
    for (int c = 0; c < 8; ++c) {
        float wa = W2[h0 + c];
        float wb = W2[HDIM + h0 + c];
#pragma unroll
        for (int r = 0; r < 4; ++r) {
            pa[r] += acc[r][c] * wa;
            pb[r] += acc[r][c] * wb;
        }
    }

    // direct bf16 store of msg rows
#pragma unroll
    for (int r = 0; r < 4; ++r) {
        int g = row0 + row_t + 16 * r;
        if (g < N) {
            uint4 pk;
            pk.x = (uint32_t)f2bf(acc[r][0]) | ((uint32_t)f2bf(acc[r][1]) << 16);
            pk.y = (uint32_t)f2bf(acc[r][2]) | ((uint32_t)f2bf(acc[r][3]) << 16);
            pk.z = (uint32_t)f2bf(acc[r][4]) | ((uint32_t)f2bf(acc[r][5]) << 16);
            pk.w = (uint32_t)f2bf(acc[r][6]) | ((uint32_t)f2bf(acc[r][7]) << 16);
            *reinterpret_cast<uint4*>(&msgb[(size_t)g * HDIM + h0]) = pk;
        }
        red_a[(row_t + 16 * r) * 17 + col_t] = pa[r];
        red_b[(row_t + 16 * r) * 17 + col_t] = pb[r];
    }
    __syncthreads();

    if (tid < K1_ROWS) {
        int g = row0 + tid;
        if (g < N) {
            float sa = 0.f, sb = 0.f;
#pragma unroll
            for (int j = 0; j < 16; ++j) {
                sa += red_a[tid * 17 + j];
                sb += red_b[tid * 17 + j];
            }
            a_src[g] = sa;
            a_dst[g] = sb;
        }
    }
}

// ---------------------------------------------------------------------------
// K23: fused edge-logit + segment softmax + weighted aggregate (r6 chassis).
// One wave per node; half-wave (32 lanes x float4) per edge, batched 8/half.
// Dot reduce: 4x DPP row_ror adds (VALU pipe) + ONE shfl_xor(16) (DS pipe)
// -> DS ops per edge drop 2.5 -> 0.5 vs the 5-stage shuffle butterfly.
// ---------------------------------------------------------------------------
#define BATCH 8   // edges per half per batch (16 edges per wave batch)

__global__ __launch_bounds__(256)
void k23_fused(const float* __restrict__ edge_emb, const float* __restrict__ W2,
               const int* __restrict__ row_ptr, const int* __restrict__ end,
               const float* __restrict__ a_src, const float* __restrict__ a_dst,
               const unsigned short* __restrict__ msgb, float* __restrict__ out,
               int N) {
    const int wid  = threadIdx.x >> 6;
    const int lane = threadIdx.x & 63;
    const int half = lane >> 5;    // 0 or 1
    const int l32  = lane & 31;
    const int n = blockIdx.x * 4 + wid;
    if (n >= N) return;

    const int lo = row_ptr[n];
    const int hi = row_ptr[n + 1];

    if (lo >= hi) {
        if (half == 0)
            *reinterpret_cast<float4*>(&out[(size_t)n * HDIM + l32 * 4]) =
                make_float4(0.f, 0.f, 0.f, 0.f);
        return;
    }

    const float4 wc = reinterpret_cast<const float4*>(W2 + 2 * HDIM)[l32];
    const float asrc = a_src[n];

    float m = -3.0e38f;
    float s = 0.f;
    float4 acc = make_float4(0.f, 0.f, 0.f, 0.f);

    for (int base = lo; base < hi; base += 2 * BATCH) {
        float lv[BATCH];
        uint2 mu[BATCH];

        // ---- pass A: independent loads + logits for 8 edges of this half ----
#pragma unroll
        for (int i = 0; i < BATCH; ++i) {
            int e = base + half + 2 * i;
            bool valid = (e < hi);
            int ee = valid ? e : (hi - 1);           // clamped, always in-bounds
            float4 ev = reinterpret_cast<const float4*>(edge_emb)[(size_t)ee * 32 + l32];
            int d = end[ee];
            mu[i] = reinterpret_cast<const uint2*>(msgb)[(size_t)d * 32 + l32];
            float p = ev.x * wc.x + ev.y * wc.y + ev.z * wc.z + ev.w * wc.w;
            // 16-lane DPP rotate-reduce (VALU) + one cross-row shuffle (DS):
            p = dpp_ror_add<8>(p);
            p = dpp_ror_add<4>(p);
            p = dpp_ror_add<2>(p);
            p = dpp_ror_add<1>(p);
            p += __shfl_xor(p, 16);                  // full 32-lane half sum
            float l = p + asrc + a_dst[d];
            l = (l >= 0.f) ? l : NEG_SLOPE * l;
            lv[i] = valid ? l : -3.0e38f;
        }

        // ---- pass B: batch max, one rescale, independent accumulates ----
        float bm = lv[0];
#pragma unroll
        for (int i = 1; i < BATCH; ++i) bm = fmaxf(bm, lv[i]);
        float mn = fmaxf(m, bm);
        float sc = __expf(m - mn);   // 0 on first batch

        float bs = 0.f;
        float4 ba = make_float4(0.f, 0.f, 0.f, 0.f);
#pragma unroll
        for (int i = 0; i < BATCH; ++i) {
            float w = __expf(lv[i] - mn);            // masked: exp(-3e38-mn)=0
            bs += w;
            ba.x += w * __uint_as_float(mu[i].x << 16);
            ba.y += w * __uint_as_float(mu[i].x & 0xffff0000u);
            ba.z += w * __uint_as_float(mu[i].y << 16);
            ba.w += w * __uint_as_float(mu[i].y & 0xffff0000u);
        }
        s = s * sc + bs;
        acc.x = acc.x * sc + ba.x;
        acc.y = acc.y * sc + ba.y;
        acc.z = acc.z * sc + ba.z;
        acc.w = acc.w * sc + ba.w;
        m = mn;
    }

    // merge the two half-wave states (empty half: m=-3e38 -> weight 0)
    float mo = __shfl_xor(m, 32);
    float so = __shfl_xor(s, 32);
    float4 ao;
    ao.x = __shfl_xor(acc.x, 32);
    ao.y = __shfl_xor(acc.y, 32);
    ao.z = __shfl_xor(acc.z, 32);
    ao.w = __shfl_xor(acc.w, 32);
    float mm = fmaxf(m, mo);
    float e0 = __expf(m - mm);
    float e1 = __expf(mo - mm);
    float inv = 1.f / (s * e0 + so * e1);
    if (half == 0) {
        float4 r;
        r.x = (acc.x * e0 + ao.x * e1) * inv;
        r.y = (acc.y * e0 + ao.y * e1) * inv;
        r.z = (acc.z * e0 + ao.z * e1) * inv;
        r.w = (acc.w * e0 + ao.w * e1) * inv;
        *reinterpret_cast<float4*>(&out[(size_t)n * HDIM + l32 * 4]) = r;
    }
}

// ---------------------------------------------------------------------------
extern "C" void kernel_launch(void* const* d_in, const int* in_sizes, int n_in,
                              void* d_out, int out_size, void* d_ws, size_t ws_size,
                              hipStream_t stream) {
    const float* node_emb = (const float*)d_in[0];
    const float* edge_emb = (const float*)d_in[1];
    const int*   start    = (const int*)d_in[2];
    const int*   end      = (const int*)d_in[3];
    const float* W1       = (const float*)d_in[4];
    const float* W2       = (const float*)d_in[5];
    float* out = (float*)d_out;

    const int N = in_sizes[0] / HDIM;
    const int E = in_sizes[2];

    uint8_t* ws = (uint8_t*)d_ws;
    size_t off = 0;
    auto alloc = [&](size_t bytes) {
        void* p = ws + off;
        off = (off + bytes + 511) & ~(size_t)511;
        return p;
    };
    unsigned short* msgb = (unsigned short*)alloc((size_t)N * HDIM * sizeof(unsigned short));
    float* a_src   = (float*)alloc((size_t)N * sizeof(float));
    float* a_dst   = (float*)alloc((size_t)N * sizeof(float));
    int*   row_ptr = (int*)alloc((size_t)(N + 1) * sizeof(int));

    // K0: row_ptr (independent of K1)
    k0_rowptr<<<(E + 255) / 256, 256, 0, stream>>>(start, row_ptr, N, E);
    // K1: messages (bf16) + fused fp32 a_src/a_dst
    k1_messages<<<(N + K1_ROWS - 1) / K1_ROWS, 256, 0, stream>>>(
        node_emb, W1, W2, msgb, a_src, a_dst, N);
    // K23: fused edge logits + batched softmax + aggregate (one wave per node)
    k23_fused<<<(N + 3) / 4, 256, 0, stream>>>(edge_emb, W2, row_ptr, end,
                                               a_src, a_dst, msgb, out, N);
}